// Round 1
// baseline (1361.629 us; speedup 1.0000x reference)
//
#include <hip/hip_runtime.h>

#define NPTS 1048576

struct DecParams {
  const float* p;
  const float* pl[12];
  const float* hash;
  const float* W0; const float* b0;
  const float* W1; const float* b1;
  const float* Wo; const float* bo;
  const float* Wc0; const float* bc0;
  const float* Wc1; const float* bc1;
  const float* Wco; const float* bco;
  float* out;
};

__device__ __forceinline__ float my_tanh(float x) {
  // tanh(x) = 1 - 2/(exp(2x)+1); exp overflow -> inf -> 1, underflow -> 0 -> -1
  float e = __expf(2.f * x);
  return 1.f - 2.f * __builtin_amdgcn_rcpf(e + 1.f);
}

__device__ __forceinline__ float my_sigmoid(float x) {
  return __builtin_amdgcn_rcpf(1.f + __expf(-x));
}

// Bilinear sample of a (3,R,R) plane, align_corners=True, border padding.
// a indexes W (x), b indexes H (y). Writes 3 channel values to f[0..2].
__device__ __forceinline__ void sample3(const float* __restrict__ pl,
                                        float a, float b, int R, float* f) {
  const float Rm1 = (float)(R - 1);
  float x = fminf(fmaxf((a + 1.f) * 0.5f * Rm1, 0.f), Rm1);
  float y = fminf(fmaxf((b + 1.f) * 0.5f * Rm1, 0.f), Rm1);
  float x0f = floorf(x), y0f = floorf(y);
  float wx = x - x0f, wy = y - y0f;
  int x0 = (int)x0f, y0 = (int)y0f;
  int x1 = min(x0 + 1, R - 1), y1 = min(y0 + 1, R - 1);
  float w00 = (1.f - wy) * (1.f - wx);
  float w01 = (1.f - wy) * wx;
  float w10 = wy * (1.f - wx);
  float w11 = wy * wx;
  int i00 = y0 * R + x0, i01 = y0 * R + x1;
  int i10 = y1 * R + x0, i11 = y1 * R + x1;
  const int R2 = R * R;
#pragma unroll
  for (int c = 0; c < 3; ++c) {
    const float* base = pl + c * R2;
    f[c] = base[i00] * w00 + base[i01] * w01 + base[i10] * w10 + base[i11] * w11;
  }
}

__global__ __launch_bounds__(256) void dec_kernel(DecParams P) {
  const int tid = blockIdx.x * 256 + threadIdx.x;

  const float* __restrict__ pp = P.p + (size_t)tid * 3;
  const float px = pp[0], py = pp[1], pz = pp[2];

  // p_nor in [-1,1): all scale factors are powers of two -> bit-exact w/ ref
  const float u = (px + 4.f) * 0.25f - 1.f;
  const float v = (py + 4.f) * 0.25f - 1.f;
  const float w = (pz + 2.f) * 0.5f - 1.f;

  float feat[68];

  // ---- tri-plane features: feat[0..35] ----
  {
    const int RES[4] = {128, 256, 512, 1024};
#pragma unroll
    for (int li = 0; li < 4; ++li) {
      sample3(P.pl[li * 3 + 0], u, v, RES[li], &feat[li * 9 + 0]);  // xy(u,v)
      sample3(P.pl[li * 3 + 1], u, w, RES[li], &feat[li * 9 + 3]);  // xz(u,w)
      sample3(P.pl[li * 3 + 2], v, w, RES[li], &feat[li * 9 + 6]);  // yz(v,w)
    }
  }

  // ---- hash-grid features: feat[36..67] ----
  {
    const float q0 = (px + 4.f) * 0.125f;  // p01 in [0,1)
    const float q1 = (py + 4.f) * 0.125f;
    const float q2 = (pz + 2.f) * 0.25f;
    const float HR[16] = {16.f, 19.f, 24.f, 30.f, 37.f, 46.f, 57.f, 71.f,
                          89.f, 110.f, 136.f, 169.f, 210.f, 260.f, 322.f, 400.f};
    const float* __restrict__ ht = P.hash;
#pragma unroll
    for (int l = 0; l < 16; ++l) {
      const float r = HR[l];
      float x0 = q0 * r, x1 = q1 * r, x2 = q2 * r;
      float f0 = floorf(x0), f1 = floorf(x1), f2 = floorf(x2);
      float w0 = x0 - f0, w1 = x1 - f1, w2 = x2 - f2;
      unsigned i0 = (unsigned)(int)f0, i1 = (unsigned)(int)f1, i2 = (unsigned)(int)f2;
      float a0 = 0.f, a1 = 0.f;
#pragma unroll
      for (int dz = 0; dz < 2; ++dz)
#pragma unroll
        for (int dy = 0; dy < 2; ++dy)
#pragma unroll
          for (int dx = 0; dx < 2; ++dx) {
            unsigned h = (i0 + dx) ^ ((i1 + dy) * 2654435761u) ^ ((i2 + dz) * 805459861u);
            unsigned idx = h & 65535u;
            const float2 tv = *(const float2*)(ht + (((unsigned)l << 16) + idx) * 2);
            float wgt = (dx ? w0 : 1.f - w0) * (dy ? w1 : 1.f - w1) * (dz ? w2 : 1.f - w2);
            a0 = fmaf(tv.x, wgt, a0);
            a1 = fmaf(tv.y, wgt, a1);
          }
      feat[36 + l * 2] = a0;
      feat[36 + l * 2 + 1] = a1;
    }
  }

  // ---- MLP (all weight reads are wave-uniform -> s_load) ----
  float acc[64];

  // layer 0: 68 -> 64, relu
#pragma unroll
  for (int j = 0; j < 64; ++j) acc[j] = P.b0[j];
#pragma unroll
  for (int i = 0; i < 68; ++i) {
    const float a = feat[i];
    const float* wr = P.W0 + i * 64;
#pragma unroll
    for (int j = 0; j < 64; ++j) acc[j] = fmaf(a, wr[j], acc[j]);
  }
  float hid[64];
#pragma unroll
  for (int j = 0; j < 64; ++j) hid[j] = fmaxf(acc[j], 0.f);

  // layer 1: 64 -> 64, relu
#pragma unroll
  for (int j = 0; j < 64; ++j) acc[j] = P.b1[j];
#pragma unroll
  for (int i = 0; i < 64; ++i) {
    const float a = hid[i];
    const float* wr = P.W1 + i * 64;
#pragma unroll
    for (int j = 0; j < 64; ++j) acc[j] = fmaf(a, wr[j], acc[j]);
  }
#pragma unroll
  for (int j = 0; j < 64; ++j) hid[j] = fmaxf(acc[j], 0.f);

  // output layer: 64 -> 33, tanh
  float so[33];
#pragma unroll
  for (int j = 0; j < 33; ++j) so[j] = P.bo[j];
#pragma unroll
  for (int i = 0; i < 64; ++i) {
    const float a = hid[i];
    const float* wr = P.Wo + i * 33;
#pragma unroll
    for (int j = 0; j < 33; ++j) so[j] = fmaf(a, wr[j], so[j]);
  }
  const float sdf = my_tanh(so[0]);
  float geo[32];
#pragma unroll
  for (int j = 0; j < 32; ++j) geo[j] = my_tanh(so[j + 1]);

  // color layer 0: [geo(32), plane_feat(36)] -> 64, relu
#pragma unroll
  for (int j = 0; j < 64; ++j) acc[j] = P.bc0[j];
#pragma unroll
  for (int i = 0; i < 32; ++i) {
    const float a = geo[i];
    const float* wr = P.Wc0 + i * 64;
#pragma unroll
    for (int j = 0; j < 64; ++j) acc[j] = fmaf(a, wr[j], acc[j]);
  }
#pragma unroll
  for (int i = 0; i < 36; ++i) {
    const float a = feat[i];
    const float* wr = P.Wc0 + (32 + i) * 64;
#pragma unroll
    for (int j = 0; j < 64; ++j) acc[j] = fmaf(a, wr[j], acc[j]);
  }
#pragma unroll
  for (int j = 0; j < 64; ++j) hid[j] = fmaxf(acc[j], 0.f);

  // color layer 1: 64 -> 32, relu
  float c1[32];
#pragma unroll
  for (int j = 0; j < 32; ++j) c1[j] = P.bc1[j];
#pragma unroll
  for (int i = 0; i < 64; ++i) {
    const float a = hid[i];
    const float* wr = P.Wc1 + i * 32;
#pragma unroll
    for (int j = 0; j < 32; ++j) c1[j] = fmaf(a, wr[j], c1[j]);
  }

  // color out: 32 -> 3, sigmoid
  float r0 = P.bco[0], r1 = P.bco[1], r2 = P.bco[2];
#pragma unroll
  for (int i = 0; i < 32; ++i) {
    const float a = fmaxf(c1[i], 0.f);
    r0 = fmaf(a, P.Wco[i * 3 + 0], r0);
    r1 = fmaf(a, P.Wco[i * 3 + 1], r1);
    r2 = fmaf(a, P.Wco[i * 3 + 2], r2);
  }

  float4 o;
  o.x = my_sigmoid(r0);
  o.y = my_sigmoid(r1);
  o.z = my_sigmoid(r2);
  o.w = sdf;
  ((float4*)P.out)[tid] = o;
}

extern "C" void kernel_launch(void* const* d_in, const int* in_sizes, int n_in,
                              void* d_out, int out_size, void* d_ws, size_t ws_size,
                              hipStream_t stream) {
  DecParams P;
  P.p = (const float*)d_in[0];
  for (int i = 0; i < 12; ++i) P.pl[i] = (const float*)d_in[1 + i];
  P.hash = (const float*)d_in[13];
  P.W0  = (const float*)d_in[14]; P.b0  = (const float*)d_in[15];
  P.W1  = (const float*)d_in[16]; P.b1  = (const float*)d_in[17];
  P.Wo  = (const float*)d_in[18]; P.bo  = (const float*)d_in[19];
  P.Wc0 = (const float*)d_in[20]; P.bc0 = (const float*)d_in[21];
  P.Wc1 = (const float*)d_in[22]; P.bc1 = (const float*)d_in[23];
  P.Wco = (const float*)d_in[24]; P.bco = (const float*)d_in[25];
  P.out = (float*)d_out;

  dec_kernel<<<NPTS / 256, 256, 0, stream>>>(P);
}

// Round 2
// 1214.077 us; speedup vs baseline: 1.1215x; 1.1215x over previous
//
#include <hip/hip_runtime.h>

#define NPTS 1048576

struct DecParams {
  const float* p;
  const float* pl[12];     // original planar f32 planes (fallback path)
  const uint2* pli[12];    // repacked interleaved bf16 planes (8B texels)
  const float* hash;
  const float* W0; const float* b0;
  const float* W1; const float* b1;
  const float* Wo; const float* bo;
  const float* Wc0; const float* bc0;
  const float* Wc1; const float* bc1;
  const float* Wco; const float* bco;
  float* out;
};

__device__ __forceinline__ float my_tanh(float x) {
  float e = __expf(2.f * x);
  return 1.f - 2.f * __builtin_amdgcn_rcpf(e + 1.f);
}

__device__ __forceinline__ float my_sigmoid(float x) {
  return __builtin_amdgcn_rcpf(1.f + __expf(-x));
}

__device__ __forceinline__ unsigned short bf16rne(float v) {
  unsigned u = __float_as_uint(v);
  unsigned r = (u + 0x7fffu + ((u >> 16) & 1u)) >> 16;
  return (unsigned short)r;
}

// unpack channel c (compile-time) of an 8B texel {bf0,bf1,bf2,pad}
__device__ __forceinline__ float texch(uint2 t, int c) {
  unsigned u = (c == 0) ? (t.x << 16) : (c == 1) ? (t.x & 0xffff0000u) : (t.y << 16);
  return __uint_as_float(u);
}

// ---- repack (3,R,R) f32 -> (R,R,4) bf16 ----
__global__ __launch_bounds__(256) void repack_kernel(const float* __restrict__ src,
                                                     ushort4* __restrict__ dst, int R) {
  int i = blockIdx.x * 256 + threadIdx.x;
  int n = R * R;
  if (i >= n) return;
  ushort4 t;
  t.x = bf16rne(src[i]);
  t.y = bf16rne(src[n + i]);
  t.z = bf16rne(src[2 * n + i]);
  t.w = 0;
  dst[i] = t;
}

// interleaved bf16 bilinear sample
__device__ __forceinline__ void sample3i(const uint2* __restrict__ pl,
                                         float a, float b, int R, float* f) {
  const float Rm1 = (float)(R - 1);
  float x = fminf(fmaxf((a + 1.f) * 0.5f * Rm1, 0.f), Rm1);
  float y = fminf(fmaxf((b + 1.f) * 0.5f * Rm1, 0.f), Rm1);
  float x0f = floorf(x), y0f = floorf(y);
  float wx = x - x0f, wy = y - y0f;
  int x0 = (int)x0f, y0 = (int)y0f;
  int x1 = min(x0 + 1, R - 1), y1 = min(y0 + 1, R - 1);
  float w00 = (1.f - wy) * (1.f - wx);
  float w01 = (1.f - wy) * wx;
  float w10 = wy * (1.f - wx);
  float w11 = wy * wx;
  uint2 t00 = pl[y0 * R + x0];
  uint2 t01 = pl[y0 * R + x1];
  uint2 t10 = pl[y1 * R + x0];
  uint2 t11 = pl[y1 * R + x1];
#pragma unroll
  for (int c = 0; c < 3; ++c) {
    f[c] = texch(t00, c) * w00 + texch(t01, c) * w01 +
           texch(t10, c) * w10 + texch(t11, c) * w11;
  }
}

// planar f32 bilinear sample (fallback)
__device__ __forceinline__ void sample3f(const float* __restrict__ pl,
                                         float a, float b, int R, float* f) {
  const float Rm1 = (float)(R - 1);
  float x = fminf(fmaxf((a + 1.f) * 0.5f * Rm1, 0.f), Rm1);
  float y = fminf(fmaxf((b + 1.f) * 0.5f * Rm1, 0.f), Rm1);
  float x0f = floorf(x), y0f = floorf(y);
  float wx = x - x0f, wy = y - y0f;
  int x0 = (int)x0f, y0 = (int)y0f;
  int x1 = min(x0 + 1, R - 1), y1 = min(y0 + 1, R - 1);
  float w00 = (1.f - wy) * (1.f - wx);
  float w01 = (1.f - wy) * wx;
  float w10 = wy * (1.f - wx);
  float w11 = wy * wx;
  int i00 = y0 * R + x0, i01 = y0 * R + x1;
  int i10 = y1 * R + x0, i11 = y1 * R + x1;
  const int R2 = R * R;
#pragma unroll
  for (int c = 0; c < 3; ++c) {
    const float* base = pl + c * R2;
    f[c] = base[i00] * w00 + base[i01] * w01 + base[i10] * w10 + base[i11] * w11;
  }
}

template <bool ILV>
__global__ __launch_bounds__(256) void dec_kernel(DecParams P) {
  const int tid = blockIdx.x * 256 + threadIdx.x;

  const float* __restrict__ pp = P.p + (size_t)tid * 3;
  const float px = pp[0], py = pp[1], pz = pp[2];

  const float u = (px + 4.f) * 0.25f - 1.f;
  const float v = (py + 4.f) * 0.25f - 1.f;
  const float w = (pz + 2.f) * 0.5f - 1.f;

  float feat[68];

  // ---- tri-plane features: feat[0..35] ----
  {
    const int RES[4] = {128, 256, 512, 1024};
#pragma unroll
    for (int li = 0; li < 4; ++li) {
      if (ILV) {
        sample3i(P.pli[li * 3 + 0], u, v, RES[li], &feat[li * 9 + 0]);
        sample3i(P.pli[li * 3 + 1], u, w, RES[li], &feat[li * 9 + 3]);
        sample3i(P.pli[li * 3 + 2], v, w, RES[li], &feat[li * 9 + 6]);
      } else {
        sample3f(P.pl[li * 3 + 0], u, v, RES[li], &feat[li * 9 + 0]);
        sample3f(P.pl[li * 3 + 1], u, w, RES[li], &feat[li * 9 + 3]);
        sample3f(P.pl[li * 3 + 2], v, w, RES[li], &feat[li * 9 + 6]);
      }
    }
  }

  // ---- hash-grid features: feat[36..67] ----
  {
    const float q0 = (px + 4.f) * 0.125f;
    const float q1 = (py + 4.f) * 0.125f;
    const float q2 = (pz + 2.f) * 0.25f;
    const float HR[16] = {16.f, 19.f, 24.f, 30.f, 37.f, 46.f, 57.f, 71.f,
                          89.f, 110.f, 136.f, 169.f, 210.f, 260.f, 322.f, 400.f};
    const float* __restrict__ ht = P.hash;
#pragma unroll
    for (int l = 0; l < 16; ++l) {
      const float r = HR[l];
      float x0 = q0 * r, x1 = q1 * r, x2 = q2 * r;
      float f0 = floorf(x0), f1 = floorf(x1), f2 = floorf(x2);
      float w0 = x0 - f0, w1 = x1 - f1, w2 = x2 - f2;
      unsigned i0 = (unsigned)(int)f0, i1 = (unsigned)(int)f1, i2 = (unsigned)(int)f2;
      float a0 = 0.f, a1 = 0.f;
#pragma unroll
      for (int dz = 0; dz < 2; ++dz)
#pragma unroll
        for (int dy = 0; dy < 2; ++dy)
#pragma unroll
          for (int dx = 0; dx < 2; ++dx) {
            unsigned h = (i0 + dx) ^ ((i1 + dy) * 2654435761u) ^ ((i2 + dz) * 805459861u);
            unsigned idx = h & 65535u;
            const float2 tv = *(const float2*)(ht + (((unsigned)l << 16) + idx) * 2);
            float wgt = (dx ? w0 : 1.f - w0) * (dy ? w1 : 1.f - w1) * (dz ? w2 : 1.f - w2);
            a0 = fmaf(tv.x, wgt, a0);
            a1 = fmaf(tv.y, wgt, a1);
          }
      feat[36 + l * 2] = a0;
      feat[36 + l * 2 + 1] = a1;
    }
  }

  // ---- MLP ----
  float acc[64];

#pragma unroll
  for (int j = 0; j < 64; ++j) acc[j] = P.b0[j];
#pragma unroll
  for (int i = 0; i < 68; ++i) {
    const float a = feat[i];
    const float* wr = P.W0 + i * 64;
#pragma unroll
    for (int j = 0; j < 64; ++j) acc[j] = fmaf(a, wr[j], acc[j]);
  }
  float hid[64];
#pragma unroll
  for (int j = 0; j < 64; ++j) hid[j] = fmaxf(acc[j], 0.f);

#pragma unroll
  for (int j = 0; j < 64; ++j) acc[j] = P.b1[j];
#pragma unroll
  for (int i = 0; i < 64; ++i) {
    const float a = hid[i];
    const float* wr = P.W1 + i * 64;
#pragma unroll
    for (int j = 0; j < 64; ++j) acc[j] = fmaf(a, wr[j], acc[j]);
  }
#pragma unroll
  for (int j = 0; j < 64; ++j) hid[j] = fmaxf(acc[j], 0.f);

  float so[33];
#pragma unroll
  for (int j = 0; j < 33; ++j) so[j] = P.bo[j];
#pragma unroll
  for (int i = 0; i < 64; ++i) {
    const float a = hid[i];
    const float* wr = P.Wo + i * 33;
#pragma unroll
    for (int j = 0; j < 33; ++j) so[j] = fmaf(a, wr[j], so[j]);
  }
  const float sdf = my_tanh(so[0]);
  float geo[32];
#pragma unroll
  for (int j = 0; j < 32; ++j) geo[j] = my_tanh(so[j + 1]);

#pragma unroll
  for (int j = 0; j < 64; ++j) acc[j] = P.bc0[j];
#pragma unroll
  for (int i = 0; i < 32; ++i) {
    const float a = geo[i];
    const float* wr = P.Wc0 + i * 64;
#pragma unroll
    for (int j = 0; j < 64; ++j) acc[j] = fmaf(a, wr[j], acc[j]);
  }
#pragma unroll
  for (int i = 0; i < 36; ++i) {
    const float a = feat[i];
    const float* wr = P.Wc0 + (32 + i) * 64;
#pragma unroll
    for (int j = 0; j < 64; ++j) acc[j] = fmaf(a, wr[j], acc[j]);
  }
#pragma unroll
  for (int j = 0; j < 64; ++j) hid[j] = fmaxf(acc[j], 0.f);

  float c1[32];
#pragma unroll
  for (int j = 0; j < 32; ++j) c1[j] = P.bc1[j];
#pragma unroll
  for (int i = 0; i < 64; ++i) {
    const float a = hid[i];
    const float* wr = P.Wc1 + i * 32;
#pragma unroll
    for (int j = 0; j < 32; ++j) c1[j] = fmaf(a, wr[j], c1[j]);
  }

  float r0 = P.bco[0], r1 = P.bco[1], r2 = P.bco[2];
#pragma unroll
  for (int i = 0; i < 32; ++i) {
    const float a = fmaxf(c1[i], 0.f);
    r0 = fmaf(a, P.Wco[i * 3 + 0], r0);
    r1 = fmaf(a, P.Wco[i * 3 + 1], r1);
    r2 = fmaf(a, P.Wco[i * 3 + 2], r2);
  }

  float4 o;
  o.x = my_sigmoid(r0);
  o.y = my_sigmoid(r1);
  o.z = my_sigmoid(r2);
  o.w = sdf;
  ((float4*)P.out)[tid] = o;
}

extern "C" void kernel_launch(void* const* d_in, const int* in_sizes, int n_in,
                              void* d_out, int out_size, void* d_ws, size_t ws_size,
                              hipStream_t stream) {
  DecParams P;
  P.p = (const float*)d_in[0];
  for (int i = 0; i < 12; ++i) P.pl[i] = (const float*)d_in[1 + i];
  P.hash = (const float*)d_in[13];
  P.W0  = (const float*)d_in[14]; P.b0  = (const float*)d_in[15];
  P.W1  = (const float*)d_in[16]; P.b1  = (const float*)d_in[17];
  P.Wo  = (const float*)d_in[18]; P.bo  = (const float*)d_in[19];
  P.Wc0 = (const float*)d_in[20]; P.bc0 = (const float*)d_in[21];
  P.Wc1 = (const float*)d_in[22]; P.bc1 = (const float*)d_in[23];
  P.Wco = (const float*)d_in[24]; P.bco = (const float*)d_in[25];
  P.out = (float*)d_out;

  const int RES[4] = {128, 256, 512, 1024};
  // ws layout: 12 planes of R*R texels, 8B each, sequential
  size_t need = 0;
  for (int i = 0; i < 12; ++i) need += (size_t)RES[i / 3] * RES[i / 3] * 8;
  need += 64;  // overread pad

  if (ws_size >= need) {
    char* wsp = (char*)d_ws;
    size_t off = 0;
    for (int i = 0; i < 12; ++i) {
      int R = RES[i / 3];
      P.pli[i] = (const uint2*)(wsp + off);
      int n = R * R;
      repack_kernel<<<(n + 255) / 256, 256, 0, stream>>>(
          (const float*)d_in[1 + i], (ushort4*)(wsp + off), R);
      off += (size_t)n * 8;
    }
    dec_kernel<true><<<NPTS / 256, 256, 0, stream>>>(P);
  } else {
    for (int i = 0; i < 12; ++i) P.pli[i] = nullptr;
    dec_kernel<false><<<NPTS / 256, 256, 0, stream>>>(P);
  }
}